// Round 3
// baseline (359.229 us; speedup 1.0000x reference)
//
#include <hip/hip_runtime.h>
#include <math.h>

#define IN_F 4096
#define OUT_F 4096
#define BATCH 256
#define TSTEPS 8

#define BM 128
#define BN 128
#define BK 32
#define KSPLIT 16
#define KLEN (IN_F / KSPLIT) /* 256 */
#define NKT (KLEN / BK)      /* 8 */
#define LDA 40               /* padded fp16 row stride: 80B -> bank spread */

typedef _Float16 f16x8 __attribute__((ext_vector_type(8)));
typedef float f32x4 __attribute__((ext_vector_type(4)));

// Split one fp32 (pre-scaled x64) into two fp16 planes: v ~= h0 + h1*2^-11.
__device__ __forceinline__ void cvt8(const float4 a, const float4 b,
                                     f16x8& h0, f16x8& h1) {
  const float v[8] = {a.x, a.y, a.z, a.w, b.x, b.y, b.z, b.w};
#pragma unroll
  for (int j = 0; j < 8; ++j) {
    const float sv = v[j] * 64.0f;
    const _Float16 c0 = (_Float16)sv;
    const float r = (sv - (float)c0) * 2048.0f;
    h0[j] = c0;
    h1[j] = (_Float16)r;
  }
}

// ---------------------------------------------------------------------------
// fp16-split MFMA GEMM: out[m][n] += sum_k x[m][k]*W[n][k]  (split-K atomic)
// 128x128 tile, 4 waves x (64x64), 16x16x32 f16 MFMA, 3 MFMAs per logical.
// KSPLIT=16 -> 1024 blocks -> 4 blocks/CU -> 4 waves/SIMD for overlap.
// ---------------------------------------------------------------------------
__global__ __launch_bounds__(256, 4) void gemm_split(
    const float* __restrict__ X, const float* __restrict__ Wt,
    float* __restrict__ out) {
  __shared__ __align__(16) _Float16 A0s[BM][LDA];
  __shared__ __align__(16) _Float16 A1s[BM][LDA];
  __shared__ __align__(16) _Float16 B0s[BN][LDA];
  __shared__ __align__(16) _Float16 B1s[BN][LDA];

  const int tid = threadIdx.x;
  const int lane = tid & 63;
  const int w = tid >> 6;
  const int wr = w & 1;
  const int wc = w >> 1;
  const int lr = lane & 15;
  const int lk = lane >> 4;

  const int m0 = blockIdx.y * BM;
  const int n0 = blockIdx.x * BN;
  const int kbeg = blockIdx.z * KLEN;

  // staging: thread owns rows (tid>>2) and (tid>>2)+64, k-chunk (tid&3)*8
  const int srow = tid >> 2;
  const int sko = (tid & 3) * 8;
  const float* pa0 = X + (size_t)(m0 + srow) * IN_F + kbeg + sko;
  const float* pa1 = pa0 + (size_t)64 * IN_F;
  const float* pb0 = Wt + (size_t)(n0 + srow) * IN_F + kbeg + sko;
  const float* pb1 = pb0 + (size_t)64 * IN_F;

  float4 ra[2][2], rb[2][2];
  ra[0][0] = *(const float4*)(pa0);
  ra[0][1] = *(const float4*)(pa0 + 4);
  ra[1][0] = *(const float4*)(pa1);
  ra[1][1] = *(const float4*)(pa1 + 4);
  rb[0][0] = *(const float4*)(pb0);
  rb[0][1] = *(const float4*)(pb0 + 4);
  rb[1][0] = *(const float4*)(pb1);
  rb[1][1] = *(const float4*)(pb1 + 4);

  f32x4 acc0[4][4], acc1[4][4];
#pragma unroll
  for (int i = 0; i < 4; ++i)
#pragma unroll
    for (int j = 0; j < 4; ++j) {
      acc0[i][j] = (f32x4){0.f, 0.f, 0.f, 0.f};
      acc1[i][j] = (f32x4){0.f, 0.f, 0.f, 0.f};
    }

  for (int kt = 0; kt < NKT; ++kt) {
    __syncthreads();  // prev iteration's LDS reads done
    f16x8 h0, h1;
    cvt8(ra[0][0], ra[0][1], h0, h1);
    *(f16x8*)&A0s[srow][sko] = h0;
    *(f16x8*)&A1s[srow][sko] = h1;
    cvt8(ra[1][0], ra[1][1], h0, h1);
    *(f16x8*)&A0s[srow + 64][sko] = h0;
    *(f16x8*)&A1s[srow + 64][sko] = h1;
    cvt8(rb[0][0], rb[0][1], h0, h1);
    *(f16x8*)&B0s[srow][sko] = h0;
    *(f16x8*)&B1s[srow][sko] = h1;
    cvt8(rb[1][0], rb[1][1], h0, h1);
    *(f16x8*)&B0s[srow + 64][sko] = h0;
    *(f16x8*)&B1s[srow + 64][sko] = h1;
    __syncthreads();

    // prefetch next k-tile into registers; latency hides under MFMAs below
    if (kt + 1 < NKT) {
      const int ko = (kt + 1) * BK;
      ra[0][0] = *(const float4*)(pa0 + ko);
      ra[0][1] = *(const float4*)(pa0 + ko + 4);
      ra[1][0] = *(const float4*)(pa1 + ko);
      ra[1][1] = *(const float4*)(pa1 + ko + 4);
      rb[0][0] = *(const float4*)(pb0 + ko);
      rb[0][1] = *(const float4*)(pb0 + ko + 4);
      rb[1][0] = *(const float4*)(pb1 + ko);
      rb[1][1] = *(const float4*)(pb1 + ko + 4);
    }

    f16x8 fa0[4], fa1[4];
#pragma unroll
    for (int i = 0; i < 4; ++i) {
      fa0[i] = *(const f16x8*)&A0s[wr * 64 + i * 16 + lr][lk * 8];
      fa1[i] = *(const f16x8*)&A1s[wr * 64 + i * 16 + lr][lk * 8];
    }
#pragma unroll
    for (int j = 0; j < 4; ++j) {
      const f16x8 fb0 = *(const f16x8*)&B0s[wc * 64 + j * 16 + lr][lk * 8];
      const f16x8 fb1 = *(const f16x8*)&B1s[wc * 64 + j * 16 + lr][lk * 8];
#pragma unroll
      for (int i = 0; i < 4; ++i) {
        acc0[i][j] = __builtin_amdgcn_mfma_f32_16x16x32_f16(fa0[i], fb0, acc0[i][j], 0, 0, 0);
        acc1[i][j] = __builtin_amdgcn_mfma_f32_16x16x32_f16(fa0[i], fb1, acc1[i][j], 0, 0, 0);
        acc1[i][j] = __builtin_amdgcn_mfma_f32_16x16x32_f16(fa1[i], fb0, acc1[i][j], 0, 0, 0);
      }
    }
  }

  // epilogue: C/D layout col=lane&15, row=(lane>>4)*4+reg (m89-verified)
#pragma unroll
  for (int i = 0; i < 4; ++i) {
    const int rbase = m0 + wr * 64 + i * 16 + lk * 4;
#pragma unroll
    for (int j = 0; j < 4; ++j) {
      const int c = n0 + wc * 64 + j * 16 + lr;
#pragma unroll
      for (int r = 0; r < 4; ++r) {
        const float val = acc0[i][j][r] * 2.44140625e-4f /* 2^-12 */ +
                          acc1[i][j][r] * 1.1920928955078125e-7f /* 2^-23 */;
        atomicAdd(&out[(size_t)(rbase + r) * OUT_F + c], val);
      }
    }
  }
}

// ---------------------------------------------------------------------------
// Fused bias + LayerNorm + tanh*|mag| + 8-step Izhikevich. 512 thr/row.
// Single-pass sum/sumsq reduction (E[x^2]-mu^2).
// ---------------------------------------------------------------------------
__global__ __launch_bounds__(512) void snn_fused(
    float* __restrict__ raw, const float* __restrict__ bias,
    const float* __restrict__ gamma, const float* __restrict__ beta,
    const float* __restrict__ cmag, const float* __restrict__ noise) {
  const int row = blockIdx.x;
  const int tid = threadIdx.x;
  const int lane = tid & 63;
  const int wid = tid >> 6;
  const int col = tid * 8;
  __shared__ float redS[8], redQ[8];

  float x[8];
#pragma unroll
  for (int p = 0; p < 2; ++p) {
    const float4 rv = *(const float4*)&raw[(size_t)row * OUT_F + col + p * 4];
    const float4 bv = *(const float4*)&bias[col + p * 4];
    x[p * 4 + 0] = rv.x + bv.x;
    x[p * 4 + 1] = rv.y + bv.y;
    x[p * 4 + 2] = rv.z + bv.z;
    x[p * 4 + 3] = rv.w + bv.w;
  }
  float s = 0.f, q = 0.f;
#pragma unroll
  for (int e = 0; e < 8; ++e) {
    s += x[e];
    q += x[e] * x[e];
  }
#pragma unroll
  for (int off = 32; off; off >>= 1) {
    s += __shfl_xor(s, off);
    q += __shfl_xor(q, off);
  }
  if (lane == 0) {
    redS[wid] = s;
    redQ[wid] = q;
  }
  __syncthreads();
  s = 0.f;
  q = 0.f;
#pragma unroll
  for (int wv = 0; wv < 8; ++wv) {
    s += redS[wv];
    q += redQ[wv];
  }
  const float mu = s * (1.0f / (float)OUT_F);
  const float var = q * (1.0f / (float)OUT_F) - mu * mu;
  const float sc = 1.0f / sqrtf(var + 1e-5f);
  const float mag = fabsf(cmag[0]);

  float I[8];
#pragma unroll
  for (int p = 0; p < 2; ++p) {
    const float4 g = *(const float4*)&gamma[col + p * 4];
    const float4 be = *(const float4*)&beta[col + p * 4];
    I[p * 4 + 0] = tanhf((x[p * 4 + 0] - mu) * sc * g.x + be.x) * mag;
    I[p * 4 + 1] = tanhf((x[p * 4 + 1] - mu) * sc * g.y + be.y) * mag;
    I[p * 4 + 2] = tanhf((x[p * 4 + 2] - mu) * sc * g.z + be.z) * mag;
    I[p * 4 + 3] = tanhf((x[p * 4 + 3] - mu) * sc * g.w + be.w) * mag;
  }

  float v[8], u[8];
  int cnt[8];
#pragma unroll
  for (int j = 0; j < 8; ++j) {
    v[j] = -65.0f;
    u[j] = -13.0f;
    cnt[j] = 0;
  }

#pragma unroll
  for (int t = 0; t < TSTEPS; ++t) {
    float nn[8];
#pragma unroll
    for (int p = 0; p < 2; ++p) {
      const float4 nz = *(const float4*)&noise[(((size_t)t * BATCH) + row) * OUT_F + col + p * 4];
      nn[p * 4 + 0] = nz.x;
      nn[p * 4 + 1] = nz.y;
      nn[p * 4 + 2] = nz.z;
      nn[p * 4 + 3] = nz.w;
    }
#pragma unroll
    for (int j = 0; j < 8; ++j) {
      const float It = I[j] + 0.3f * nn[j];
      const float vv = v[j];
      const float dv = (0.04f * vv * vv + 5.0f * vv + 140.0f - u[j] + It) * 0.5f;
      const float du = 0.02f * (0.2f * vv - u[j]) * 0.5f;
      float vn = vv + dv;
      vn = fminf(fmaxf(vn, -100.0f), 60.0f);
      float un = u[j] + du;
      un = fminf(fmaxf(un, -100.0f), 100.0f);
      const bool sp = (vn >= 30.0f);
      v[j] = sp ? -65.0f : vn;
      u[j] = sp ? (un + 8.0f) : un;
      cnt[j] += sp ? 1 : 0;
    }
  }

#pragma unroll
  for (int p = 0; p < 2; ++p) {
    float4 o;
    o.x = (float)cnt[p * 4 + 0] * 0.125f;
    o.y = (float)cnt[p * 4 + 1] * 0.125f;
    o.z = (float)cnt[p * 4 + 2] * 0.125f;
    o.w = (float)cnt[p * 4 + 3] * 0.125f;
    *(float4*)&raw[(size_t)row * OUT_F + col + p * 4] = o;
  }
}

extern "C" void kernel_launch(void* const* d_in, const int* in_sizes, int n_in,
                              void* d_out, int out_size, void* d_ws, size_t ws_size,
                              hipStream_t stream) {
  const float* x = (const float*)d_in[0];
  const float* W = (const float*)d_in[1];
  const float* b = (const float*)d_in[2];
  const float* gam = (const float*)d_in[3];
  const float* bet = (const float*)d_in[4];
  const float* cmag = (const float*)d_in[5];
  const float* nz = (const float*)d_in[6];
  float* out = (float*)d_out;
  (void)d_ws;
  (void)ws_size;

  // d_out doubles as the raw-GEMM accumulator (split-K atomics need zeros)
  hipMemsetAsync(out, 0, (size_t)BATCH * OUT_F * sizeof(float), stream);

  dim3 grid1(OUT_F / BN, BATCH / BM, KSPLIT);
  gemm_split<<<grid1, 256, 0, stream>>>(x, W, out);

  snn_fused<<<BATCH, 512, 0, stream>>>(out, b, gam, bet, cmag, nz);
}

// Round 5
// 184.241 us; speedup vs baseline: 1.9498x; 1.9498x over previous
//
#include <hip/hip_runtime.h>
#include <math.h>

#define IN_F 4096
#define OUT_F 4096
#define BATCH 256
#define TSTEPS 8

#define BM 128
#define BN 64
#define BK 32
#define KSPLIT 8
#define KLEN (IN_F / KSPLIT) /* 512 */
#define NKT (KLEN / BK)      /* 16 */
#define LDA 40               /* padded fp16 row stride: 80B -> bank spread */

typedef _Float16 f16x8 __attribute__((ext_vector_type(8)));
typedef float f32x4 __attribute__((ext_vector_type(4)));

// Split one fp32 (pre-scaled x64) into two fp16 planes: v ~= h0 + h1*2^-11.
__device__ __forceinline__ void cvt8(const float4 a, const float4 b,
                                     f16x8& h0, f16x8& h1) {
  const float v[8] = {a.x, a.y, a.z, a.w, b.x, b.y, b.z, b.w};
#pragma unroll
  for (int j = 0; j < 8; ++j) {
    const float sv = v[j] * 64.0f;
    const _Float16 c0 = (_Float16)sv;
    const float r = (sv - (float)c0) * 2048.0f;
    h0[j] = c0;
    h1[j] = (_Float16)r;
  }
}

// ---------------------------------------------------------------------------
// fp16-split MFMA GEMM: out[m][n] += sum_k x[m][k]*W[n][k]  (split-K atomic)
// 128x64 tile, 4 waves x (32x64), 16x16x32 f16 MFMA, 3 MFMAs per logical.
// Register footprint ~105 (acc 64 + frags + staging) -> 4 blocks/CU honest.
// ---------------------------------------------------------------------------
__global__ __launch_bounds__(256, 4) void gemm_split(
    const float* __restrict__ X, const float* __restrict__ Wt,
    float* __restrict__ out) {
  __shared__ __align__(16) _Float16 A0s[BM][LDA];
  __shared__ __align__(16) _Float16 A1s[BM][LDA];
  __shared__ __align__(16) _Float16 B0s[BN][LDA];
  __shared__ __align__(16) _Float16 B1s[BN][LDA];

  const int tid = threadIdx.x;
  const int lane = tid & 63;
  const int w = tid >> 6;      // wave 0..3 -> owns rows w*32..w*32+31
  const int lr = lane & 15;
  const int lk = lane >> 4;

  const int m0 = blockIdx.y * BM;
  const int n0 = blockIdx.x * BN;
  const int kbeg = blockIdx.z * KLEN;

  // staging: A row = tid>>1 (16 floats at (tid&1)*16); B row = tid>>2 (8 at (tid&3)*8)
  const int arow = tid >> 1;
  const int ako = (tid & 1) * 16;
  const int brow = tid >> 2;
  const int bko = (tid & 3) * 8;
  const float* pa = X + (size_t)(m0 + arow) * IN_F + kbeg + ako;
  const float* pb = Wt + (size_t)(n0 + brow) * IN_F + kbeg + bko;

  f32x4 acc0[2][4], acc1[2][4];
#pragma unroll
  for (int i = 0; i < 2; ++i)
#pragma unroll
    for (int j = 0; j < 4; ++j) {
      acc0[i][j] = (f32x4){0.f, 0.f, 0.f, 0.f};
      acc1[i][j] = (f32x4){0.f, 0.f, 0.f, 0.f};
    }

  for (int kt = 0; kt < NKT; ++kt) {
    const int ko = kt * BK;
    __syncthreads();  // prev iteration's LDS reads done
    {
      const float4 a0 = *(const float4*)(pa + ko);
      const float4 a1 = *(const float4*)(pa + ko + 4);
      const float4 a2 = *(const float4*)(pa + ko + 8);
      const float4 a3 = *(const float4*)(pa + ko + 12);
      const float4 b0 = *(const float4*)(pb + ko);
      const float4 b1 = *(const float4*)(pb + ko + 4);
      f16x8 h0, h1;
      cvt8(a0, a1, h0, h1);
      *(f16x8*)&A0s[arow][ako] = h0;
      *(f16x8*)&A1s[arow][ako] = h1;
      cvt8(a2, a3, h0, h1);
      *(f16x8*)&A0s[arow][ako + 8] = h0;
      *(f16x8*)&A1s[arow][ako + 8] = h1;
      cvt8(b0, b1, h0, h1);
      *(f16x8*)&B0s[brow][bko] = h0;
      *(f16x8*)&B1s[brow][bko] = h1;
    }
    __syncthreads();

    f16x8 fa0[2], fa1[2];
#pragma unroll
    for (int i = 0; i < 2; ++i) {
      fa0[i] = *(const f16x8*)&A0s[w * 32 + i * 16 + lr][lk * 8];
      fa1[i] = *(const f16x8*)&A1s[w * 32 + i * 16 + lr][lk * 8];
    }
#pragma unroll
    for (int j = 0; j < 4; ++j) {
      const f16x8 fb0 = *(const f16x8*)&B0s[j * 16 + lr][lk * 8];
      const f16x8 fb1 = *(const f16x8*)&B1s[j * 16 + lr][lk * 8];
#pragma unroll
      for (int i = 0; i < 2; ++i) {
        acc0[i][j] = __builtin_amdgcn_mfma_f32_16x16x32_f16(fa0[i], fb0, acc0[i][j], 0, 0, 0);
        acc1[i][j] = __builtin_amdgcn_mfma_f32_16x16x32_f16(fa0[i], fb1, acc1[i][j], 0, 0, 0);
        acc1[i][j] = __builtin_amdgcn_mfma_f32_16x16x32_f16(fa1[i], fb0, acc1[i][j], 0, 0, 0);
      }
    }
  }

  // epilogue: C/D layout col=lane&15, row=(lane>>4)*4+reg (m89-verified)
#pragma unroll
  for (int i = 0; i < 2; ++i) {
    const int rbase = m0 + w * 32 + i * 16 + lk * 4;
#pragma unroll
    for (int j = 0; j < 4; ++j) {
      const int c = n0 + j * 16 + lr;
#pragma unroll
      for (int r = 0; r < 4; ++r) {
        const float val = acc0[i][j][r] * 2.44140625e-4f /* 2^-12 */ +
                          acc1[i][j][r] * 1.1920928955078125e-7f /* 2^-23 */;
        atomicAdd(&out[(size_t)(rbase + r) * OUT_F + c], val);
      }
    }
  }
}

// ---------------------------------------------------------------------------
// Fused bias + LayerNorm + tanh*|mag| + 8-step Izhikevich. 512 thr/row.
// Single-pass sum/sumsq reduction (E[x^2]-mu^2).
// ---------------------------------------------------------------------------
__global__ __launch_bounds__(512) void snn_fused(
    float* __restrict__ raw, const float* __restrict__ bias,
    const float* __restrict__ gamma, const float* __restrict__ beta,
    const float* __restrict__ cmag, const float* __restrict__ noise) {
  const int row = blockIdx.x;
  const int tid = threadIdx.x;
  const int lane = tid & 63;
  const int wid = tid >> 6;
  const int col = tid * 8;
  __shared__ float redS[8], redQ[8];

  float x[8];
#pragma unroll
  for (int p = 0; p < 2; ++p) {
    const float4 rv = *(const float4*)&raw[(size_t)row * OUT_F + col + p * 4];
    const float4 bv = *(const float4*)&bias[col + p * 4];
    x[p * 4 + 0] = rv.x + bv.x;
    x[p * 4 + 1] = rv.y + bv.y;
    x[p * 4 + 2] = rv.z + bv.z;
    x[p * 4 + 3] = rv.w + bv.w;
  }
  float s = 0.f, q = 0.f;
#pragma unroll
  for (int e = 0; e < 8; ++e) {
    s += x[e];
    q += x[e] * x[e];
  }
#pragma unroll
  for (int off = 32; off; off >>= 1) {
    s += __shfl_xor(s, off);
    q += __shfl_xor(q, off);
  }
  if (lane == 0) {
    redS[wid] = s;
    redQ[wid] = q;
  }
  __syncthreads();
  s = 0.f;
  q = 0.f;
#pragma unroll
  for (int wv = 0; wv < 8; ++wv) {
    s += redS[wv];
    q += redQ[wv];
  }
  const float mu = s * (1.0f / (float)OUT_F);
  const float var = q * (1.0f / (float)OUT_F) - mu * mu;
  const float sc = 1.0f / sqrtf(var + 1e-5f);
  const float mag = fabsf(cmag[0]);

  float I[8];
#pragma unroll
  for (int p = 0; p < 2; ++p) {
    const float4 g = *(const float4*)&gamma[col + p * 4];
    const float4 be = *(const float4*)&beta[col + p * 4];
    I[p * 4 + 0] = tanhf((x[p * 4 + 0] - mu) * sc * g.x + be.x) * mag;
    I[p * 4 + 1] = tanhf((x[p * 4 + 1] - mu) * sc * g.y + be.y) * mag;
    I[p * 4 + 2] = tanhf((x[p * 4 + 2] - mu) * sc * g.z + be.z) * mag;
    I[p * 4 + 3] = tanhf((x[p * 4 + 3] - mu) * sc * g.w + be.w) * mag;
  }

  float v[8], u[8];
  int cnt[8];
#pragma unroll
  for (int j = 0; j < 8; ++j) {
    v[j] = -65.0f;
    u[j] = -13.0f;
    cnt[j] = 0;
  }

#pragma unroll
  for (int t = 0; t < TSTEPS; ++t) {
    float nn[8];
#pragma unroll
    for (int p = 0; p < 2; ++p) {
      const float4 nz = *(const float4*)&noise[(((size_t)t * BATCH) + row) * OUT_F + col + p * 4];
      nn[p * 4 + 0] = nz.x;
      nn[p * 4 + 1] = nz.y;
      nn[p * 4 + 2] = nz.z;
      nn[p * 4 + 3] = nz.w;
    }
#pragma unroll
    for (int j = 0; j < 8; ++j) {
      const float It = I[j] + 0.3f * nn[j];
      const float vv = v[j];
      const float dv = (0.04f * vv * vv + 5.0f * vv + 140.0f - u[j] + It) * 0.5f;
      const float du = 0.02f * (0.2f * vv - u[j]) * 0.5f;
      float vn = vv + dv;
      vn = fminf(fmaxf(vn, -100.0f), 60.0f);
      float un = u[j] + du;
      un = fminf(fmaxf(un, -100.0f), 100.0f);
      const bool sp = (vn >= 30.0f);
      v[j] = sp ? -65.0f : vn;
      u[j] = sp ? (un + 8.0f) : un;
      cnt[j] += sp ? 1 : 0;
    }
  }

#pragma unroll
  for (int p = 0; p < 2; ++p) {
    float4 o;
    o.x = (float)cnt[p * 4 + 0] * 0.125f;
    o.y = (float)cnt[p * 4 + 1] * 0.125f;
    o.z = (float)cnt[p * 4 + 2] * 0.125f;
    o.w = (float)cnt[p * 4 + 3] * 0.125f;
    *(float4*)&raw[(size_t)row * OUT_F + col + p * 4] = o;
  }
}

extern "C" void kernel_launch(void* const* d_in, const int* in_sizes, int n_in,
                              void* d_out, int out_size, void* d_ws, size_t ws_size,
                              hipStream_t stream) {
  const float* x = (const float*)d_in[0];
  const float* W = (const float*)d_in[1];
  const float* b = (const float*)d_in[2];
  const float* gam = (const float*)d_in[3];
  const float* bet = (const float*)d_in[4];
  const float* cmag = (const float*)d_in[5];
  const float* nz = (const float*)d_in[6];
  float* out = (float*)d_out;
  (void)d_ws;
  (void)ws_size;

  // d_out doubles as the raw-GEMM accumulator (split-K atomics need zeros)
  hipMemsetAsync(out, 0, (size_t)BATCH * OUT_F * sizeof(float), stream);

  dim3 grid1(OUT_F / BN, BATCH / BM, KSPLIT);
  gemm_split<<<grid1, 256, 0, stream>>>(x, W, out);

  snn_fused<<<BATCH, 512, 0, stream>>>(out, b, gam, bet, cmag, nz);
}